// Round 15
// baseline (562.150 us; speedup 1.0000x reference)
//
#include <hip/hip_runtime.h>
#include <hip/hip_bf16.h>

#define N_NODES 100000
#define NFEAT 9
#define HID 128
#define B_GRAPHS 64
#define SEQ_LEN 768
#define HD 256
#define L_LAYERS 4
#define LN_EPS 1e-5f

typedef __attribute__((ext_vector_type(8))) short short8;
typedef __attribute__((ext_vector_type(4))) float f32x4;

__device__ __forceinline__ float lrelu(float v) { return v > 0.f ? v : 0.2f * v; }

__device__ __forceinline__ float wave_sum64(float x) {
#pragma unroll
  for (int o = 32; o >= 1; o >>= 1) x += __shfl_xor(x, o, 64);
  return x;
}

__device__ __forceinline__ unsigned short bf16r(float v) {
  unsigned int u = __float_as_uint(v);
  return (unsigned short)((u + 0x7fffu + ((u >> 16) & 1u)) >> 16);
}
// pack: low16 = bf16(lo), high16 = bf16(hi)
__device__ __forceinline__ unsigned int bf16pair(float lo, float hi) {
  unsigned int ul = __float_as_uint(lo);
  unsigned int uh = __float_as_uint(hi);
  ul = (ul + 0x7fffu + ((ul >> 16) & 1u)) >> 16;
  uh = (uh + 0x7fffu + ((uh >> 16) & 1u)) & 0xffff0000u;
  return ul | uh;
}
__device__ __forceinline__ float bflo(unsigned int u) { return __uint_as_float(u << 16); }
__device__ __forceinline__ float bfhi(unsigned int u) { return __uint_as_float(u & 0xffff0000u); }

// h = relu(x @ ne_W.T + ne_b) -> bf16 hb only
__global__ __launch_bounds__(256) void ne_kernel(const float* __restrict__ x,
                                                 const float* __restrict__ W,
                                                 const float* __restrict__ b,
                                                 unsigned short* __restrict__ hb) {
  int idx = blockIdx.x * 256 + threadIdx.x;
  int n = idx >> 7, c = idx & 127;
  const float* xr = x + n * NFEAT;
  const float* wr = W + c * NFEAT;
  float acc = b[c];
#pragma unroll
  for (int k = 0; k < NFEAT; ++k) acc += xr[k] * wr[k];
  acc = fmaxf(acc, 0.f);
  hb[idx] = bf16r(acc);
}

// convert all L layers of gat_W to bf16
__global__ __launch_bounds__(256) void wcvt_kernel(const float* __restrict__ W,
                                                   unsigned short* __restrict__ wb) {
  int idx = blockIdx.x * 256 + threadIdx.x;
  if (idx < L_LAYERS * HID * HID) wb[idx] = bf16r(W[idx]);
}

// was8[l][j][k]: j<4: sum_c W[l][j*32+c][k]*asrc[l][j*32+c]; j in 4..7: adst; j>=8: 0
__global__ __launch_bounds__(256) void wprep_kernel(const float* __restrict__ W,
                                                    const float* __restrict__ asrc,
                                                    const float* __restrict__ adst,
                                                    unsigned short* __restrict__ was8) {
  int t = blockIdx.x * 256 + threadIdx.x;  // L*16*128
  if (t >= L_LAYERS * 16 * 128) return;
  int l = t >> 11;
  int rem = t & 2047;
  int j = rem >> 7;
  int k = rem & 127;
  float sum = 0.f;
  if (j < 8) {
    int head = j & 3;
    const float* a = (j < 4) ? (asrc + l * HID + head * 32) : (adst + l * HID + head * 32);
    const float* Wl = W + (size_t)l * HID * HID + (size_t)(head * 32) * HID + k;
#pragma unroll 8
    for (int c = 0; c < 32; ++c) sum += Wl[(size_t)c * HID] * a[c];
  }
  was8[t] = bf16r(sum);
}

__global__ __launch_bounds__(256) void hist_kernel(const int* __restrict__ dst,
                                                   int* __restrict__ cnt, int E) {
  int i = blockIdx.x * 256 + threadIdx.x;
  if (i < E) atomicAdd(&cnt[dst[i]], 1);
}

// hierarchical exclusive scan
__global__ __launch_bounds__(1024) void scan1_kernel(const int* __restrict__ cnt,
                                                     int* __restrict__ off,
                                                     int* __restrict__ bsum, int n) {
  __shared__ int ws[16];
  __shared__ int wx[16];
  int tid = threadIdx.x, lane = tid & 63, w = tid >> 6;
  int i = blockIdx.x * 1024 + tid;
  int v = (i < n) ? cnt[i] : 0;
  int x = v;
#pragma unroll
  for (int o = 1; o < 64; o <<= 1) {
    int t = __shfl_up(x, o, 64);
    if (lane >= o) x += t;
  }
  if (lane == 63) ws[w] = x;
  __syncthreads();
  if (tid == 0) {
    int r = 0;
#pragma unroll
    for (int j = 0; j < 16; ++j) { int t = ws[j]; wx[j] = r; r += t; }
    bsum[blockIdx.x] = r;
  }
  __syncthreads();
  if (i < n) off[i] = wx[w] + x - v;
}

__global__ void scan2_kernel(int* __restrict__ bsum, int nb) {
  int lane = threadIdx.x;
  int i0 = lane * 2, i1 = i0 + 1;
  int a = (i0 < nb) ? bsum[i0] : 0;
  int b = (i1 < nb) ? bsum[i1] : 0;
  int s = a + b, x = s;
#pragma unroll
  for (int o = 1; o < 64; o <<= 1) {
    int t = __shfl_up(x, o, 64);
    if (lane >= o) x += t;
  }
  int excl = x - s;
  if (i0 < nb) bsum[i0] = excl;
  if (i1 < nb) bsum[i1] = excl + a;
}

__global__ __launch_bounds__(256) void scan3_kernel(const int* __restrict__ bsum,
                                                    int* __restrict__ off, int n, int total) {
  int i = blockIdx.x * 256 + threadIdx.x;
  if (i < n) off[i] += bsum[i >> 10];
  else if (i == n) off[i] = total;
}

// stores PRE-SCALED src offsets (src*256 BYTES into xlp) for cheap gathers downstream
__global__ __launch_bounds__(256) void scatter_kernel(const int* __restrict__ src,
                                                      const int* __restrict__ dst,
                                                      const int* __restrict__ off,
                                                      int* __restrict__ cur,
                                                      int* __restrict__ eadj, int E) {
  int i = blockIdx.x * 256 + threadIdx.x;
  if (i < E) {
    int d = dst[i];
    int pos = atomicAdd(&cur[d], 1);
    eadj[off[d] + pos] = src[i] << 8;
  }
}

// xl = h @ W.T via bf16 MFMA. 128 rows/block, 4 waves (32 rows each).
// NO LDS: W (32KB bf16) is L1-resident; B-fragments read direct from global.
// Logits computed with one extra MFMA B-operand (was8), no shuffles.
__global__ __launch_bounds__(256) void gat_xl_kernel(const unsigned short* __restrict__ hb,
                                                     const unsigned short* __restrict__ wb,
                                                     const unsigned short* __restrict__ wasb,
                                                     unsigned int* __restrict__ xlp,
                                                     float* __restrict__ esrc,
                                                     float* __restrict__ edst) {
  const int tid = threadIdx.x;
  const int lane = tid & 63;
  const int wv = tid >> 6;
  const int base = blockIdx.x * 128;
  const int l15 = lane & 15;
  const int lg = lane >> 4;  // 0..3

  f32x4 acc[2][8];
  f32x4 acc_e[2];
#pragma unroll
  for (int rb = 0; rb < 2; ++rb) {
#pragma unroll
    for (int nb = 0; nb < 8; ++nb) acc[rb][nb] = (f32x4){0.f, 0.f, 0.f, 0.f};
    acc_e[rb] = (f32x4){0.f, 0.f, 0.f, 0.f};
  }

  int n0 = base + wv * 32 + l15;
  int n1 = n0 + 16;
  if (n0 >= N_NODES) n0 = N_NODES - 1;
  if (n1 >= N_NODES) n1 = N_NODES - 1;
  const size_t rowA0 = (size_t)n0 * HID;
  const size_t rowA1 = (size_t)n1 * HID;
  const unsigned short* wrow = wb + (size_t)l15 * HID;  // row l15 (+16*nb below)

#pragma unroll
  for (int kc = 0; kc < 4; ++kc) {
    const int kb = kc * 32 + lg * 8;
    short8 a0 = *(const short8*)(hb + rowA0 + kb);
    short8 a1 = *(const short8*)(hb + rowA1 + kb);
    short8 efrag = *(const short8*)(wasb + l15 * HID + kb);
    acc_e[0] = __builtin_amdgcn_mfma_f32_16x16x32_bf16(a0, efrag, acc_e[0], 0, 0, 0);
    acc_e[1] = __builtin_amdgcn_mfma_f32_16x16x32_bf16(a1, efrag, acc_e[1], 0, 0, 0);
#pragma unroll
    for (int nb = 0; nb < 8; ++nb) {
      short8 bfrag = *(const short8*)(wrow + (size_t)(nb * 16) * HID + kb);
      acc[0][nb] = __builtin_amdgcn_mfma_f32_16x16x32_bf16(a0, bfrag, acc[0][nb], 0, 0, 0);
      acc[1][nb] = __builtin_amdgcn_mfma_f32_16x16x32_bf16(a1, bfrag, acc[1][nb], 0, 0, 0);
    }
  }

#pragma unroll
  for (int rb = 0; rb < 2; ++rb) {
#pragma unroll
    for (int r = 0; r < 4; ++r) {
      int node = base + wv * 32 + rb * 16 + lg * 4 + r;
      if (node < N_NODES) {
#pragma unroll
        for (int nb = 0; nb < 4; ++nb) {
          unsigned int pk = bf16pair(acc[rb][nb][r], acc[rb][nb + 4][r]);
          xlp[(size_t)node * 64 + nb * 16 + l15] = pk;
        }
        float ev = acc_e[rb][r];
        if (l15 < 4) esrc[node * 4 + l15] = ev;
        else if (l15 < 8) edst[node * 4 + (l15 - 4)] = ev;
      }
    }
  }
}

// single-pass softmax aggregation with INLINE edge weights (edgew fused).
// TWO nodes per wave (lanes 0-31: node A, lanes 32-63: node B). Each lane owns
// 4 channels. eadj entries are src*256 byte offsets; padded with zeroed ints.
// Per edge: esrc[src] is a per-half BROADCAST float4; q computed in fp32.
__global__ __launch_bounds__(256) void gat_agg_kernel(const unsigned int* __restrict__ xlp,
                                                      const float* __restrict__ esrc,
                                                      const float* __restrict__ edst,
                                                      const int* __restrict__ off,
                                                      const int* __restrict__ eadj,
                                                      const float* __restrict__ gbias,
                                                      const float* __restrict__ lng,
                                                      const float* __restrict__ lnb,
                                                      unsigned short* __restrict__ hb) {
  const int tid = threadIdx.x;
  const int lane = tid & 63;
  const int hl = lane & 31;
  const int half = lane >> 5;
  const int node = blockIdx.x * 8 + (tid >> 6) * 2 + half;
  const int h0 = hl >> 4;  // head for channels 2hl,2hl+1 (h0+2 for +64)

  // per-lane dst logits for its two heads
  const float4 ed = *(const float4*)(edst + (size_t)node * 4);
  const float edA = h0 ? ed.y : ed.x;
  const float edB = h0 ? ed.w : ed.z;

  // prologue: self-loop
  const float4 es0v = *(const float4*)(esrc + (size_t)node * 4);
  float wA = __expf(lrelu((h0 ? es0v.y : es0v.x) + edA));
  float wB = __expf(lrelu((h0 ? es0v.w : es0v.z) + edB));
  float sA = wA, sB = wB;
  const char* xpb = (const char*)xlp + (hl << 3);  // per-lane uint2 base
  const char* esb = (const char*)esrc;
  const uint2 vi = *(const uint2*)(xpb + ((unsigned)node << 8));
  float acc0 = bflo(vi.x) * wA;
  float acc1 = bflo(vi.y) * wA;
  float acc2 = bfhi(vi.x) * wB;
  float acc3 = bfhi(vi.y) * wB;

  const int beg = off[node], end = off[node + 1];
  int j = beg;
  int4 ea;
  if (j < end) ea = *(const int4*)(eadj + j);
  for (; j + 4 <= end;) {
    const int4 eaC = ea;
    const int jn = j + 4;
    if (jn < end) ea = *(const int4*)(eadj + jn);  // prefetch (padded-safe)
    const uint2 v0 = *(const uint2*)(xpb + (unsigned)eaC.x);
    const uint2 v1 = *(const uint2*)(xpb + (unsigned)eaC.y);
    const uint2 v2 = *(const uint2*)(xpb + (unsigned)eaC.z);
    const uint2 v3 = *(const uint2*)(xpb + (unsigned)eaC.w);
    const float4 e0 = *(const float4*)(esb + ((unsigned)eaC.x >> 4));
    const float4 e1 = *(const float4*)(esb + ((unsigned)eaC.y >> 4));
    const float4 e2 = *(const float4*)(esb + ((unsigned)eaC.z >> 4));
    const float4 e3 = *(const float4*)(esb + ((unsigned)eaC.w >> 4));
    float qA0 = __expf(lrelu((h0 ? e0.y : e0.x) + edA));
    float qB0 = __expf(lrelu((h0 ? e0.w : e0.z) + edB));
    float qA1 = __expf(lrelu((h0 ? e1.y : e1.x) + edA));
    float qB1 = __expf(lrelu((h0 ? e1.w : e1.z) + edB));
    float qA2 = __expf(lrelu((h0 ? e2.y : e2.x) + edA));
    float qB2 = __expf(lrelu((h0 ? e2.w : e2.z) + edB));
    float qA3 = __expf(lrelu((h0 ? e3.y : e3.x) + edA));
    float qB3 = __expf(lrelu((h0 ? e3.w : e3.z) + edB));
    sA += qA0 + qA1 + qA2 + qA3;
    sB += qB0 + qB1 + qB2 + qB3;
    acc0 = fmaf(bflo(v0.x), qA0, acc0);
    acc1 = fmaf(bflo(v0.y), qA0, acc1);
    acc2 = fmaf(bfhi(v0.x), qB0, acc2);
    acc3 = fmaf(bfhi(v0.y), qB0, acc3);
    acc0 = fmaf(bflo(v1.x), qA1, acc0);
    acc1 = fmaf(bflo(v1.y), qA1, acc1);
    acc2 = fmaf(bfhi(v1.x), qB1, acc2);
    acc3 = fmaf(bfhi(v1.y), qB1, acc3);
    acc0 = fmaf(bflo(v2.x), qA2, acc0);
    acc1 = fmaf(bflo(v2.y), qA2, acc1);
    acc2 = fmaf(bfhi(v2.x), qB2, acc2);
    acc3 = fmaf(bfhi(v2.y), qB2, acc3);
    acc0 = fmaf(bflo(v3.x), qA3, acc0);
    acc1 = fmaf(bflo(v3.y), qA3, acc1);
    acc2 = fmaf(bfhi(v3.x), qB3, acc2);
    acc3 = fmaf(bfhi(v3.y), qB3, acc3);
    j = jn;
  }
  if (j < end) {  // masked tail round (eadj padded: reads are safe)
    const int4 eaC = ea;
    const uint2 v0 = *(const uint2*)(xpb + (unsigned)eaC.x);
    const uint2 v1 = *(const uint2*)(xpb + (unsigned)eaC.y);
    const uint2 v2 = *(const uint2*)(xpb + (unsigned)eaC.z);
    const uint2 v3 = *(const uint2*)(xpb + (unsigned)eaC.w);
    const float4 e0 = *(const float4*)(esb + ((unsigned)eaC.x >> 4));
    const float4 e1 = *(const float4*)(esb + ((unsigned)eaC.y >> 4));
    const float4 e2 = *(const float4*)(esb + ((unsigned)eaC.z >> 4));
    const float4 e3 = *(const float4*)(esb + ((unsigned)eaC.w >> 4));
    float qA0 = __expf(lrelu((h0 ? e0.y : e0.x) + edA));
    float qB0 = __expf(lrelu((h0 ? e0.w : e0.z) + edB));
    float qA1 = __expf(lrelu((h0 ? e1.y : e1.x) + edA));
    float qB1 = __expf(lrelu((h0 ? e1.w : e1.z) + edB));
    float qA2 = __expf(lrelu((h0 ? e2.y : e2.x) + edA));
    float qB2 = __expf(lrelu((h0 ? e2.w : e2.z) + edB));
    float qA3 = __expf(lrelu((h0 ? e3.y : e3.x) + edA));
    float qB3 = __expf(lrelu((h0 ? e3.w : e3.z) + edB));
    const int r = end - j;  // 1..3
    if (r < 2) { qA1 = 0.f; qB1 = 0.f; }
    if (r < 3) { qA2 = 0.f; qB2 = 0.f; }
    qA3 = 0.f; qB3 = 0.f;
    sA += qA0 + qA1 + qA2 + qA3;
    sB += qB0 + qB1 + qB2 + qB3;
    acc0 = fmaf(bflo(v0.x), qA0, acc0);
    acc1 = fmaf(bflo(v0.y), qA0, acc1);
    acc2 = fmaf(bfhi(v0.x), qB0, acc2);
    acc3 = fmaf(bfhi(v0.y), qB0, acc3);
    acc0 = fmaf(bflo(v1.x), qA1, acc0);
    acc1 = fmaf(bflo(v1.y), qA1, acc1);
    acc2 = fmaf(bfhi(v1.x), qB1, acc2);
    acc3 = fmaf(bfhi(v1.y), qB1, acc3);
    acc0 = fmaf(bflo(v2.x), qA2, acc0);
    acc1 = fmaf(bflo(v2.y), qA2, acc1);
    acc2 = fmaf(bfhi(v2.x), qB2, acc2);
    acc3 = fmaf(bfhi(v2.y), qB2, acc3);
    acc0 = fmaf(bflo(v3.x), qA3, acc0);
    acc1 = fmaf(bflo(v3.y), qA3, acc1);
    acc2 = fmaf(bfhi(v3.x), qB3, acc2);
    acc3 = fmaf(bfhi(v3.y), qB3, acc3);
  }

  const float invA = 1.f / (sA + 1e-16f);
  const float invB = 1.f / (sB + 1e-16f);
  const float2 gb0 = *(const float2*)(gbias + 2 * hl);
  const float2 gb1 = *(const float2*)(gbias + 64 + 2 * hl);
  float o0 = acc0 * invA + gb0.x;
  float o1 = acc1 * invA + gb0.y;
  float o2 = acc2 * invB + gb1.x;
  float o3 = acc3 * invB + gb1.y;
  // two-moment LN over the 32-lane half (128 channels)
  float s1 = o0 + o1 + o2 + o3;
  float s2 = o0 * o0 + o1 * o1 + o2 * o2 + o3 * o3;
#pragma unroll
  for (int o = 16; o >= 1; o >>= 1) {
    s1 += __shfl_xor(s1, o, 64);
    s2 += __shfl_xor(s2, o, 64);
  }
  float mu = s1 * (1.f / 128.f);
  float var = fmaxf(s2 * (1.f / 128.f) - mu * mu, 0.f);
  float rn = rsqrtf(var + LN_EPS);
  const float2 lg0 = *(const float2*)(lng + 2 * hl);
  const float2 lg1 = *(const float2*)(lng + 64 + 2 * hl);
  const float2 lb0 = *(const float2*)(lnb + 2 * hl);
  const float2 lb1 = *(const float2*)(lnb + 64 + 2 * hl);
  float hn0 = fmaxf((o0 - mu) * rn * lg0.x + lb0.x, 0.f);
  float hn1 = fmaxf((o1 - mu) * rn * lg0.y + lb0.y, 0.f);
  float hn2 = fmaxf((o2 - mu) * rn * lg1.x + lb1.x, 0.f);
  float hn3 = fmaxf((o3 - mu) * rn * lg1.y + lb1.y, 0.f);
  unsigned int* hrow = (unsigned int*)(hb + (size_t)node * HID);
  unsigned int h01 = hrow[hl];        // channels 2hl (low16), 2hl+1 (high16)
  unsigned int h23 = hrow[32 + hl];   // channels 2hl+64, 2hl+65
  float nh0 = bflo(h01) + hn0;
  float nh1 = bfhi(h01) + hn1;
  float nh2 = bflo(h23) + hn2;
  float nh3 = bfhi(h23) + hn3;
  hrow[hl] = bf16pair(nh0, nh1);
  hrow[32 + hl] = bf16pair(nh2, nh3);
}

__device__ __forceinline__ int lower_bound_dev(const int* a, int n, int v) {
  int lo = 0, hi = n;
  while (lo < hi) {
    int mid = (lo + hi) >> 1;
    if (a[mid] < v) lo = mid + 1; else hi = mid;
  }
  return lo;
}

// pooling stage 1: partial sums; grid (B, 4 col-groups, 8 row-chunks)
__global__ __launch_bounds__(256) void pool_part_kernel(const unsigned short* __restrict__ hb,
                                                        const int* __restrict__ batch,
                                                        float* __restrict__ ppart) {
  __shared__ float red[256];
  int b = blockIdx.x, tid = threadIdx.x;
  int start = lower_bound_dev(batch, N_NODES, b);
  int end = lower_bound_dev(batch, N_NODES, b + 1);
  int cl = tid & 31, g = tid >> 5;           // 8 row-groups of 32 lanes
  int c = cl + blockIdx.y * 32;
  int rowoff = blockIdx.z * 8 + g;           // 0..63
  float acc = 0.f;
  for (int n = start + rowoff; n < end; n += 64)
    acc += __uint_as_float((unsigned int)hb[(size_t)n * HID + c] << 16);
  red[tid] = acc;
  __syncthreads();
  if (g == 0) {
    float tot = 0.f;
#pragma unroll
    for (int k = 0; k < 8; ++k) tot += red[cl + 32 * k];
    ppart[((size_t)b * 8 + blockIdx.z) * HID + c] = tot;
  }
}

// pooling stage 2: sum 8 partials, divide by count. grid B, 128 threads.
__global__ __launch_bounds__(128) void pool_reduce_kernel(const float* __restrict__ ppart,
                                                          const int* __restrict__ batch,
                                                          float* __restrict__ pooled) {
  int b = blockIdx.x, c = threadIdx.x;
  int start = lower_bound_dev(batch, N_NODES, b);
  int end = lower_bound_dev(batch, N_NODES, b + 1);
  float tot = 0.f;
#pragma unroll
  for (int z = 0; z < 8; ++z) tot += ppart[((size_t)b * 8 + z) * HID + c];
  float cntf = fmaxf((float)(end - start), 1.f);
  pooled[b * HID + c] = tot / cntf;
}

// One wave per output element (m,c); lane-split K; two independent fused stages.
__global__ __launch_bounds__(256) void gemv2_kernel(
    const float* __restrict__ A1, int lda1, const float* __restrict__ W1,
    const float* __restrict__ b1, float* __restrict__ O1, int ldo1,
    int sh1, int K1, int relu1,
    const float* __restrict__ A2, int lda2, const float* __restrict__ W2,
    const float* __restrict__ b2, float* __restrict__ O2, int ldo2,
    int sh2, int K2, int relu2, int nw1, int nwTot) {
  int gw = (blockIdx.x * 256 + threadIdx.x) >> 6;
  int lane = threadIdx.x & 63;
  if (gw >= nwTot) return;
  const float *A, *W, *b;
  float* O;
  int lda, ldo, K, relu, m, c;
  if (gw < nw1) {
    A = A1; W = W1; b = b1; O = O1; lda = lda1; ldo = ldo1; K = K1; relu = relu1;
    m = gw >> sh1; c = gw & ((1 << sh1) - 1);
  } else {
    int g2 = gw - nw1;
    A = A2; W = W2; b = b2; O = O2; lda = lda2; ldo = ldo2; K = K2; relu = relu2;
    m = g2 >> sh2; c = g2 & ((1 << sh2) - 1);
  }
  const float* a = A + (size_t)m * lda;
  const float* w = W + (size_t)c * K;
  float acc = 0.f;
  for (int k = lane * 2; k < K; k += 128) {
    float2 av = *(const float2*)(a + k);
    float2 wv = *(const float2*)(w + k);
    acc += av.x * wv.x + av.y * wv.y;
  }
  acc = wave_sum64(acc);
  if (lane == 0) {
    acc += b[c];
    if (relu) acc = fmaxf(acc, 0.f);
    O[(size_t)m * ldo + c] = acc;
  }
}

// z1 = relu([att1|att2|seqh|strh] @ p1_W.T + p1_b); wave per (m,c)
__global__ __launch_bounds__(256) void z1_kernel(const float* __restrict__ att1,
                                                 const float* __restrict__ att2,
                                                 const float* __restrict__ seqh,
                                                 const float* __restrict__ strh,
                                                 const float* __restrict__ p1_W,
                                                 const float* __restrict__ p1_b,
                                                 float* __restrict__ z1) {
  int gw = (blockIdx.x * 256 + threadIdx.x) >> 6;
  int lane = threadIdx.x & 63;
  int m = gw >> 8, c = gw & 255;
  const float* segs[4] = {att1 + m * HD, att2 + m * HD, seqh + m * HD, strh + m * HD};
  const float* w = p1_W + (size_t)c * (4 * HD);
  float acc = 0.f;
#pragma unroll
  for (int s = 0; s < 4; ++s) {
    const float* a = segs[s];
#pragma unroll
    for (int k = lane * 2; k < HD; k += 128) {
      float2 av = *(const float2*)(a + k);
      float2 wv = *(const float2*)(w + s * HD + k);
      acc += av.x * wv.x + av.y * wv.y;
    }
  }
  acc = wave_sum64(acc);
  if (lane == 0) z1[m * HD + c] = fmaxf(acc + p1_b[c], 0.f);
}

extern "C" void kernel_launch(void* const* d_in, const int* in_sizes, int n_in,
                              void* d_out, int out_size, void* d_ws, size_t ws_size,
                              hipStream_t stream) {
  const float* seq_emb = (const float*)d_in[0];
  const float* x       = (const float*)d_in[1];
  const int* eidx      = (const int*)d_in[2];
  const int* batch     = (const int*)d_in[3];
  const float* ne_W = (const float*)d_in[4];
  const float* ne_b = (const float*)d_in[5];
  const float* gat_W = (const float*)d_in[6];
  const float* gat_asrc = (const float*)d_in[7];
  const float* gat_adst = (const float*)d_in[8];
  const float* gat_b = (const float*)d_in[9];
  const float* ln_g = (const float*)d_in[10];
  const float* ln_b = (const float*)d_in[11];
  const float* op1_W = (const float*)d_in[12];
  const float* op1_b = (const float*)d_in[13];
  const float* op2_W = (const float*)d_in[14];
  const float* op2_b = (const float*)d_in[15];
  const float* sp_W = (const float*)d_in[16];
  const float* sp_b = (const float*)d_in[17];
  const float* stp_W = (const float*)d_in[18];
  const float* stp_b = (const float*)d_in[19];
  const float* a1_Wi = (const float*)d_in[20];
  const float* a1_bi = (const float*)d_in[21];
  const float* a1_Wo = (const float*)d_in[22];
  const float* a1_bo = (const float*)d_in[23];
  const float* a2_Wi = (const float*)d_in[24];
  const float* a2_bi = (const float*)d_in[25];
  const float* a2_Wo = (const float*)d_in[26];
  const float* a2_bo = (const float*)d_in[27];
  const float* p1_W = (const float*)d_in[28];
  const float* p1_b = (const float*)d_in[29];
  const float* p2_W = (const float*)d_in[30];
  const float* p2_b = (const float*)d_in[31];
  const float* p3_W = (const float*)d_in[32];
  const float* p3_b = (const float*)d_in[33];

  const int E = in_sizes[2] / 2;
  const int* e_src = eidx;
  const int* e_dst = eidx + E;

  char* p = (char*)d_ws;
  auto alloc = [&](size_t bytes) -> void* {
    void* r = p;
    p += (bytes + 255) & ~(size_t)255;
    return r;
  };
  unsigned short* hbuf = (unsigned short*)alloc(sizeof(unsigned short) * (size_t)N_NODES * HID);
  unsigned short* wb   = (unsigned short*)alloc(sizeof(unsigned short) * L_LAYERS * HID * HID);
  unsigned short* was8 = (unsigned short*)alloc(sizeof(unsigned short) * L_LAYERS * 16 * HID);
  unsigned int* xlp = (unsigned int*)alloc(sizeof(unsigned int) * (size_t)N_NODES * 64);
  float* esrc = (float*)alloc(sizeof(float) * (size_t)N_NODES * 4);
  float* edst = (float*)alloc(sizeof(float) * (size_t)N_NODES * 4);
  int* cnt    = (int*)alloc(sizeof(int) * N_NODES);
  int* cur    = (int*)alloc(sizeof(int) * N_NODES);
  int* off    = (int*)alloc(sizeof(int) * (N_NODES + 1));
  int* eadj   = (int*)alloc(sizeof(int) * ((size_t)E + 8));
  int* bsum   = (int*)alloc(sizeof(int) * 128);
  float* ppart = (float*)alloc(sizeof(float) * B_GRAPHS * 8 * HID);
  float* pooled = (float*)alloc(sizeof(float) * B_GRAPHS * HID);
  float* t1B   = (float*)alloc(sizeof(float) * B_GRAPHS * HID);
  float* sembB = (float*)alloc(sizeof(float) * B_GRAPHS * HID);
  float* seqhB = (float*)alloc(sizeof(float) * B_GRAPHS * HD);
  float* strhB = (float*)alloc(sizeof(float) * B_GRAPHS * HD);
  float* v1B   = (float*)alloc(sizeof(float) * B_GRAPHS * HD);
  float* v2B   = (float*)alloc(sizeof(float) * B_GRAPHS * HD);
  float* att1B = (float*)alloc(sizeof(float) * B_GRAPHS * HD);
  float* att2B = (float*)alloc(sizeof(float) * B_GRAPHS * HD);
  float* z1B   = (float*)alloc(sizeof(float) * B_GRAPHS * HD);
  float* z2B   = (float*)alloc(sizeof(float) * B_GRAPHS * (HD / 2));

  hipMemsetAsync(cnt, 0, sizeof(int) * N_NODES, stream);
  hipMemsetAsync(cur, 0, sizeof(int) * N_NODES, stream);
  hipMemsetAsync(eadj + E, 0, sizeof(int) * 8, stream);  // tail-round pad

  const int SCAN_BLKS = (N_NODES + 1023) / 1024;  // 98
  ne_kernel<<<N_NODES * HID / 256, 256, 0, stream>>>(x, ne_W, ne_b, hbuf);
  wcvt_kernel<<<(L_LAYERS * HID * HID + 255) / 256, 256, 0, stream>>>(gat_W, wb);
  wprep_kernel<<<(L_LAYERS * 16 * 128 + 255) / 256, 256, 0, stream>>>(gat_W, gat_asrc, gat_adst, was8);
  hist_kernel<<<(E + 255) / 256, 256, 0, stream>>>(e_dst, cnt, E);
  scan1_kernel<<<SCAN_BLKS, 1024, 0, stream>>>(cnt, off, bsum, N_NODES);
  scan2_kernel<<<1, 64, 0, stream>>>(bsum, SCAN_BLKS);
  scan3_kernel<<<(N_NODES + 256) / 256, 256, 0, stream>>>(bsum, off, N_NODES, E);
  scatter_kernel<<<(E + 255) / 256, 256, 0, stream>>>(e_src, e_dst, off, cur, eadj, E);

  for (int l = 0; l < L_LAYERS; ++l) {
    gat_xl_kernel<<<(N_NODES + 127) / 128, 256, 0, stream>>>(
        hbuf, wb + (size_t)l * HID * HID, was8 + (size_t)l * 16 * HID,
        xlp, esrc, edst);
    gat_agg_kernel<<<N_NODES / 8, 256, 0, stream>>>(
        xlp, esrc, edst, off, eadj, gat_b + l * HID, ln_g + l * HID, ln_b + l * HID,
        hbuf);
  }
  pool_part_kernel<<<dim3(B_GRAPHS, 4, 8), 256, 0, stream>>>(hbuf, batch, ppart);
  pool_reduce_kernel<<<B_GRAPHS, 128, 0, stream>>>(ppart, batch, pooled);

  // ---- head: 8 dependency levels, wave-per-output ----
  const float* a1_Wv = a1_Wi + 2 * HD * HD;
  const float* a1_bv = a1_bi + 2 * HD;
  const float* a2_Wv = a2_Wi + 2 * HD * HD;
  const float* a2_bv = a2_bi + 2 * HD;
  auto nblk = [](int waves) { return (unsigned)((waves + 3) / 4); };

  {
    int nw1 = B_GRAPHS * HD, nwT = nw1 + B_GRAPHS * HID;
    gemv2_kernel<<<nblk(nwT), 256, 0, stream>>>(
        seq_emb, SEQ_LEN, sp_W, sp_b, seqhB, HD, 8, SEQ_LEN, 0,
        pooled, HID, op1_W, op1_b, t1B, HID, 7, HID, 1, nw1, nwT);
  }
  {
    int nw1 = B_GRAPHS * HD, nwT = nw1 + B_GRAPHS * HID;
    gemv2_kernel<<<nblk(nwT), 256, 0, stream>>>(
        seqhB, HD, a2_Wv, a2_bv, v2B, HD, 8, HD, 0,
        t1B, HID, op2_W, op2_b, sembB, HID, 7, HID, 0, nw1, nwT);
  }
  {
    int nw1 = B_GRAPHS * HD, nwT = nw1 + B_GRAPHS * HD;
    gemv2_kernel<<<nblk(nwT), 256, 0, stream>>>(
        v2B, HD, a2_Wo, a2_bo, att2B, HD, 8, HD, 0,
        sembB, HID, stp_W, stp_b, strhB, HD, 8, HID, 0, nw1, nwT);
  }
  {
    int nwT = B_GRAPHS * HD;
    gemv2_kernel<<<nblk(nwT), 256, 0, stream>>>(
        strhB, HD, a1_Wv, a1_bv, v1B, HD, 8, HD, 0,
        nullptr, 0, nullptr, nullptr, nullptr, 0, 0, 0, 0, nwT, nwT);
  }
  {
    int nwT = B_GRAPHS * HD;
    gemv2_kernel<<<nblk(nwT), 256, 0, stream>>>(
        v1B, HD, a1_Wo, a1_bo, att1B, HD, 8, HD, 0,
        nullptr, 0, nullptr, nullptr, nullptr, 0, 0, 0, 0, nwT, nwT);
  }
  z1_kernel<<<nblk(B_GRAPHS * HD), 256, 0, stream>>>(att1B, att2B, seqhB, strhB, p1_W, p1_b, z1B);
  {
    int nwT = B_GRAPHS * (HD / 2);
    gemv2_kernel<<<nblk(nwT), 256, 0, stream>>>(
        z1B, HD, p2_W, p2_b, z2B, HD / 2, 7, HD, 1,
        nullptr, 0, nullptr, nullptr, nullptr, 0, 0, 0, 0, nwT, nwT);
  }
  {
    int nwT = B_GRAPHS;
    gemv2_kernel<<<nblk(nwT), 256, 0, stream>>>(
        z2B, HD / 2, p3_W, p3_b, (float*)d_out, 1, 0, HD / 2, 0,
        nullptr, 0, nullptr, nullptr, nullptr, 0, 0, 0, 0, nwT, nwT);
  }
}

// Round 16
// 491.188 us; speedup vs baseline: 1.1445x; 1.1445x over previous
//
#include <hip/hip_runtime.h>
#include <hip/hip_bf16.h>

#define N_NODES 100000
#define NFEAT 9
#define HID 128
#define B_GRAPHS 64
#define SEQ_LEN 768
#define HD 256
#define L_LAYERS 4
#define LN_EPS 1e-5f

typedef __attribute__((ext_vector_type(8))) short short8;
typedef __attribute__((ext_vector_type(4))) float f32x4;

__device__ __forceinline__ float lrelu(float v) { return v > 0.f ? v : 0.2f * v; }

__device__ __forceinline__ float wave_sum64(float x) {
#pragma unroll
  for (int o = 32; o >= 1; o >>= 1) x += __shfl_xor(x, o, 64);
  return x;
}

__device__ __forceinline__ unsigned short bf16r(float v) {
  unsigned int u = __float_as_uint(v);
  return (unsigned short)((u + 0x7fffu + ((u >> 16) & 1u)) >> 16);
}
// pack: low16 = bf16(lo), high16 = bf16(hi)
__device__ __forceinline__ unsigned int bf16pair(float lo, float hi) {
  unsigned int ul = __float_as_uint(lo);
  unsigned int uh = __float_as_uint(hi);
  ul = (ul + 0x7fffu + ((ul >> 16) & 1u)) >> 16;
  uh = (uh + 0x7fffu + ((uh >> 16) & 1u)) & 0xffff0000u;
  return ul | uh;
}
__device__ __forceinline__ float bflo(unsigned int u) { return __uint_as_float(u << 16); }
__device__ __forceinline__ float bfhi(unsigned int u) { return __uint_as_float(u & 0xffff0000u); }

// h = relu(x @ ne_W.T + ne_b) -> bf16 hb only
__global__ __launch_bounds__(256) void ne_kernel(const float* __restrict__ x,
                                                 const float* __restrict__ W,
                                                 const float* __restrict__ b,
                                                 unsigned short* __restrict__ hb) {
  int idx = blockIdx.x * 256 + threadIdx.x;
  int n = idx >> 7, c = idx & 127;
  const float* xr = x + n * NFEAT;
  const float* wr = W + c * NFEAT;
  float acc = b[c];
#pragma unroll
  for (int k = 0; k < NFEAT; ++k) acc += xr[k] * wr[k];
  acc = fmaxf(acc, 0.f);
  hb[idx] = bf16r(acc);
}

// convert all L layers of gat_W to bf16
__global__ __launch_bounds__(256) void wcvt_kernel(const float* __restrict__ W,
                                                   unsigned short* __restrict__ wb) {
  int idx = blockIdx.x * 256 + threadIdx.x;
  if (idx < L_LAYERS * HID * HID) wb[idx] = bf16r(W[idx]);
}

// was8[l][j][k]: j<4: sum_c W[l][j*32+c][k]*asrc[l][j*32+c]; j in 4..7: adst; j>=8: 0
__global__ __launch_bounds__(256) void wprep_kernel(const float* __restrict__ W,
                                                    const float* __restrict__ asrc,
                                                    const float* __restrict__ adst,
                                                    unsigned short* __restrict__ was8) {
  int t = blockIdx.x * 256 + threadIdx.x;  // L*16*128
  if (t >= L_LAYERS * 16 * 128) return;
  int l = t >> 11;
  int rem = t & 2047;
  int j = rem >> 7;
  int k = rem & 127;
  float sum = 0.f;
  if (j < 8) {
    int head = j & 3;
    const float* a = (j < 4) ? (asrc + l * HID + head * 32) : (adst + l * HID + head * 32);
    const float* Wl = W + (size_t)l * HID * HID + (size_t)(head * 32) * HID + k;
#pragma unroll 8
    for (int c = 0; c < 32; ++c) sum += Wl[(size_t)c * HID] * a[c];
  }
  was8[t] = bf16r(sum);
}

__global__ __launch_bounds__(256) void hist_kernel(const int* __restrict__ dst,
                                                   int* __restrict__ cnt, int E) {
  int i = blockIdx.x * 256 + threadIdx.x;
  if (i < E) atomicAdd(&cnt[dst[i]], 1);
}

// hierarchical exclusive scan
__global__ __launch_bounds__(1024) void scan1_kernel(const int* __restrict__ cnt,
                                                     int* __restrict__ off,
                                                     int* __restrict__ bsum, int n) {
  __shared__ int ws[16];
  __shared__ int wx[16];
  int tid = threadIdx.x, lane = tid & 63, w = tid >> 6;
  int i = blockIdx.x * 1024 + tid;
  int v = (i < n) ? cnt[i] : 0;
  int x = v;
#pragma unroll
  for (int o = 1; o < 64; o <<= 1) {
    int t = __shfl_up(x, o, 64);
    if (lane >= o) x += t;
  }
  if (lane == 63) ws[w] = x;
  __syncthreads();
  if (tid == 0) {
    int r = 0;
#pragma unroll
    for (int j = 0; j < 16; ++j) { int t = ws[j]; wx[j] = r; r += t; }
    bsum[blockIdx.x] = r;
  }
  __syncthreads();
  if (i < n) off[i] = wx[w] + x - v;
}

__global__ void scan2_kernel(int* __restrict__ bsum, int nb) {
  int lane = threadIdx.x;
  int i0 = lane * 2, i1 = i0 + 1;
  int a = (i0 < nb) ? bsum[i0] : 0;
  int b = (i1 < nb) ? bsum[i1] : 0;
  int s = a + b, x = s;
#pragma unroll
  for (int o = 1; o < 64; o <<= 1) {
    int t = __shfl_up(x, o, 64);
    if (lane >= o) x += t;
  }
  int excl = x - s;
  if (i0 < nb) bsum[i0] = excl;
  if (i1 < nb) bsum[i1] = excl + a;
}

__global__ __launch_bounds__(256) void scan3_kernel(const int* __restrict__ bsum,
                                                    int* __restrict__ off, int n, int total) {
  int i = blockIdx.x * 256 + threadIdx.x;
  if (i < n) off[i] += bsum[i >> 10];
  else if (i == n) off[i] = total;
}

// stores PRE-SCALED src offsets (src*256 BYTES into xlp) for cheap gathers downstream
__global__ __launch_bounds__(256) void scatter_kernel(const int* __restrict__ src,
                                                      const int* __restrict__ dst,
                                                      const int* __restrict__ off,
                                                      int* __restrict__ cur,
                                                      int* __restrict__ eadj, int E) {
  int i = blockIdx.x * 256 + threadIdx.x;
  if (i < E) {
    int d = dst[i];
    int pos = atomicAdd(&cur[d], 1);
    eadj[off[d] + pos] = src[i] << 8;
  }
}

// xl = h @ W.T via bf16 MFMA. 256 rows/block, 8 waves (32 rows each); W staged
// in LDS once per 256 rows. Logits via extra MFMA B-operand (was8), no shuffles.
__global__ __launch_bounds__(512) void gat_xl_kernel(const unsigned short* __restrict__ hb,
                                                     const unsigned short* __restrict__ wb,
                                                     const unsigned short* __restrict__ wasb,
                                                     unsigned int* __restrict__ xlp,
                                                     float* __restrict__ esrc,
                                                     float* __restrict__ edst) {
  __shared__ unsigned short Wl[128][136];  // +8 pad: 2-way bank alias only
  const int tid = threadIdx.x;
  const int lane = tid & 63;
  const int wv = tid >> 6;  // 0..7
  const int base = blockIdx.x * 256;
  const int l15 = lane & 15;
  const int lg = lane >> 4;  // 0..3

  // stage W (bf16) into LDS: 2048 uint4 chunks / 512 threads = 4 iters
#pragma unroll
  for (int t = 0; t < 4; ++t) {
    int f8 = tid + t * 512;
    int row = f8 >> 4, c8 = (f8 & 15) * 8;
    uint4 v = *(const uint4*)(wb + row * HID + c8);
    *(uint4*)&Wl[row][c8] = v;
  }
  __syncthreads();

  f32x4 acc[2][8];
  f32x4 acc_e[2];
#pragma unroll
  for (int rb = 0; rb < 2; ++rb) {
#pragma unroll
    for (int nb = 0; nb < 8; ++nb) acc[rb][nb] = (f32x4){0.f, 0.f, 0.f, 0.f};
    acc_e[rb] = (f32x4){0.f, 0.f, 0.f, 0.f};
  }

  int n0 = base + wv * 32 + l15;
  int n1 = n0 + 16;
  if (n0 >= N_NODES) n0 = N_NODES - 1;
  if (n1 >= N_NODES) n1 = N_NODES - 1;
  const size_t rowA0 = (size_t)n0 * HID;
  const size_t rowA1 = (size_t)n1 * HID;

#pragma unroll
  for (int kc = 0; kc < 4; ++kc) {
    const int kb = kc * 32 + lg * 8;
    short8 a0 = *(const short8*)(hb + rowA0 + kb);
    short8 a1 = *(const short8*)(hb + rowA1 + kb);
    short8 efrag = *(const short8*)(wasb + l15 * HID + kb);
    acc_e[0] = __builtin_amdgcn_mfma_f32_16x16x32_bf16(a0, efrag, acc_e[0], 0, 0, 0);
    acc_e[1] = __builtin_amdgcn_mfma_f32_16x16x32_bf16(a1, efrag, acc_e[1], 0, 0, 0);
#pragma unroll
    for (int nb = 0; nb < 8; ++nb) {
      short8 bfrag = *(const short8*)&Wl[nb * 16 + l15][kb];
      acc[0][nb] = __builtin_amdgcn_mfma_f32_16x16x32_bf16(a0, bfrag, acc[0][nb], 0, 0, 0);
      acc[1][nb] = __builtin_amdgcn_mfma_f32_16x16x32_bf16(a1, bfrag, acc[1][nb], 0, 0, 0);
    }
  }

#pragma unroll
  for (int rb = 0; rb < 2; ++rb) {
#pragma unroll
    for (int r = 0; r < 4; ++r) {
      int node = base + wv * 32 + rb * 16 + lg * 4 + r;
      if (node < N_NODES) {
#pragma unroll
        for (int nb = 0; nb < 4; ++nb) {
          unsigned int pk = bf16pair(acc[rb][nb][r], acc[rb][nb + 4][r]);
          xlp[(size_t)node * 64 + nb * 16 + l15] = pk;
        }
        float ev = acc_e[rb][r];
        if (l15 < 4) esrc[node * 4 + l15] = ev;
        else if (l15 < 8) edst[node * 4 + (l15 - 4)] = ev;
      }
    }
  }
}

// single-pass softmax aggregation with INLINE edge weights (edgew fused).
// TWO nodes per wave (lanes 0-31: node A, lanes 32-63: node B). Each lane owns
// 4 channels. eadj entries are src*256 byte offsets; padded with zeroed ints.
// Per edge: esrc[src] is a per-half BROADCAST float4; q computed in fp32.
__global__ __launch_bounds__(256) void gat_agg_kernel(const unsigned int* __restrict__ xlp,
                                                      const float* __restrict__ esrc,
                                                      const float* __restrict__ edst,
                                                      const int* __restrict__ off,
                                                      const int* __restrict__ eadj,
                                                      const float* __restrict__ gbias,
                                                      const float* __restrict__ lng,
                                                      const float* __restrict__ lnb,
                                                      unsigned short* __restrict__ hb) {
  const int tid = threadIdx.x;
  const int lane = tid & 63;
  const int hl = lane & 31;
  const int half = lane >> 5;
  const int node = blockIdx.x * 8 + (tid >> 6) * 2 + half;
  const int h0 = hl >> 4;  // head for channels 2hl,2hl+1 (h0+2 for +64)

  // per-lane dst logits for its two heads
  const float4 ed = *(const float4*)(edst + (size_t)node * 4);
  const float edA = h0 ? ed.y : ed.x;
  const float edB = h0 ? ed.w : ed.z;

  // prologue: self-loop
  const float4 es0v = *(const float4*)(esrc + (size_t)node * 4);
  float wA = __expf(lrelu((h0 ? es0v.y : es0v.x) + edA));
  float wB = __expf(lrelu((h0 ? es0v.w : es0v.z) + edB));
  float sA = wA, sB = wB;
  const char* xpb = (const char*)xlp + (hl << 3);  // per-lane uint2 base
  const char* esb = (const char*)esrc;
  const uint2 vi = *(const uint2*)(xpb + ((unsigned)node << 8));
  float acc0 = bflo(vi.x) * wA;
  float acc1 = bflo(vi.y) * wA;
  float acc2 = bfhi(vi.x) * wB;
  float acc3 = bfhi(vi.y) * wB;

  const int beg = off[node], end = off[node + 1];
  int j = beg;
  int4 ea;
  if (j < end) ea = *(const int4*)(eadj + j);
  for (; j + 4 <= end;) {
    const int4 eaC = ea;
    const int jn = j + 4;
    if (jn < end) ea = *(const int4*)(eadj + jn);  // prefetch (padded-safe)
    const uint2 v0 = *(const uint2*)(xpb + (unsigned)eaC.x);
    const uint2 v1 = *(const uint2*)(xpb + (unsigned)eaC.y);
    const uint2 v2 = *(const uint2*)(xpb + (unsigned)eaC.z);
    const uint2 v3 = *(const uint2*)(xpb + (unsigned)eaC.w);
    const float4 e0 = *(const float4*)(esb + ((unsigned)eaC.x >> 4));
    const float4 e1 = *(const float4*)(esb + ((unsigned)eaC.y >> 4));
    const float4 e2 = *(const float4*)(esb + ((unsigned)eaC.z >> 4));
    const float4 e3 = *(const float4*)(esb + ((unsigned)eaC.w >> 4));
    float qA0 = __expf(lrelu((h0 ? e0.y : e0.x) + edA));
    float qB0 = __expf(lrelu((h0 ? e0.w : e0.z) + edB));
    float qA1 = __expf(lrelu((h0 ? e1.y : e1.x) + edA));
    float qB1 = __expf(lrelu((h0 ? e1.w : e1.z) + edB));
    float qA2 = __expf(lrelu((h0 ? e2.y : e2.x) + edA));
    float qB2 = __expf(lrelu((h0 ? e2.w : e2.z) + edB));
    float qA3 = __expf(lrelu((h0 ? e3.y : e3.x) + edA));
    float qB3 = __expf(lrelu((h0 ? e3.w : e3.z) + edB));
    sA += qA0 + qA1 + qA2 + qA3;
    sB += qB0 + qB1 + qB2 + qB3;
    acc0 = fmaf(bflo(v0.x), qA0, acc0);
    acc1 = fmaf(bflo(v0.y), qA0, acc1);
    acc2 = fmaf(bfhi(v0.x), qB0, acc2);
    acc3 = fmaf(bfhi(v0.y), qB0, acc3);
    acc0 = fmaf(bflo(v1.x), qA1, acc0);
    acc1 = fmaf(bflo(v1.y), qA1, acc1);
    acc2 = fmaf(bfhi(v1.x), qB1, acc2);
    acc3 = fmaf(bfhi(v1.y), qB1, acc3);
    acc0 = fmaf(bflo(v2.x), qA2, acc0);
    acc1 = fmaf(bflo(v2.y), qA2, acc1);
    acc2 = fmaf(bfhi(v2.x), qB2, acc2);
    acc3 = fmaf(bfhi(v2.y), qB2, acc3);
    acc0 = fmaf(bflo(v3.x), qA3, acc0);
    acc1 = fmaf(bflo(v3.y), qA3, acc1);
    acc2 = fmaf(bfhi(v3.x), qB3, acc2);
    acc3 = fmaf(bfhi(v3.y), qB3, acc3);
    j = jn;
  }
  if (j < end) {  // masked tail round (eadj padded: reads are safe)
    const int4 eaC = ea;
    const uint2 v0 = *(const uint2*)(xpb + (unsigned)eaC.x);
    const uint2 v1 = *(const uint2*)(xpb + (unsigned)eaC.y);
    const uint2 v2 = *(const uint2*)(xpb + (unsigned)eaC.z);
    const uint2 v3 = *(const uint2*)(xpb + (unsigned)eaC.w);
    const float4 e0 = *(const float4*)(esb + ((unsigned)eaC.x >> 4));
    const float4 e1 = *(const float4*)(esb + ((unsigned)eaC.y >> 4));
    const float4 e2 = *(const float4*)(esb + ((unsigned)eaC.z >> 4));
    const float4 e3 = *(const float4*)(esb + ((unsigned)eaC.w >> 4));
    float qA0 = __expf(lrelu((h0 ? e0.y : e0.x) + edA));
    float qB0 = __expf(lrelu((h0 ? e0.w : e0.z) + edB));
    float qA1 = __expf(lrelu((h0 ? e1.y : e1.x) + edA));
    float qB1 = __expf(lrelu((h0 ? e1.w : e1.z) + edB));
    float qA2 = __expf(lrelu((h0 ? e2.y : e2.x) + edA));
    float qB2 = __expf(lrelu((h0 ? e2.w : e2.z) + edB));
    float qA3 = __expf(lrelu((h0 ? e3.y : e3.x) + edA));
    float qB3 = __expf(lrelu((h0 ? e3.w : e3.z) + edB));
    const int r = end - j;  // 1..3
    if (r < 2) { qA1 = 0.f; qB1 = 0.f; }
    if (r < 3) { qA2 = 0.f; qB2 = 0.f; }
    qA3 = 0.f; qB3 = 0.f;
    sA += qA0 + qA1 + qA2 + qA3;
    sB += qB0 + qB1 + qB2 + qB3;
    acc0 = fmaf(bflo(v0.x), qA0, acc0);
    acc1 = fmaf(bflo(v0.y), qA0, acc1);
    acc2 = fmaf(bfhi(v0.x), qB0, acc2);
    acc3 = fmaf(bfhi(v0.y), qB0, acc3);
    acc0 = fmaf(bflo(v1.x), qA1, acc0);
    acc1 = fmaf(bflo(v1.y), qA1, acc1);
    acc2 = fmaf(bfhi(v1.x), qB1, acc2);
    acc3 = fmaf(bfhi(v1.y), qB1, acc3);
    acc0 = fmaf(bflo(v2.x), qA2, acc0);
    acc1 = fmaf(bflo(v2.y), qA2, acc1);
    acc2 = fmaf(bfhi(v2.x), qB2, acc2);
    acc3 = fmaf(bfhi(v2.y), qB2, acc3);
    acc0 = fmaf(bflo(v3.x), qA3, acc0);
    acc1 = fmaf(bflo(v3.y), qA3, acc1);
    acc2 = fmaf(bfhi(v3.x), qB3, acc2);
    acc3 = fmaf(bfhi(v3.y), qB3, acc3);
  }

  const float invA = 1.f / (sA + 1e-16f);
  const float invB = 1.f / (sB + 1e-16f);
  const float2 gb0 = *(const float2*)(gbias + 2 * hl);
  const float2 gb1 = *(const float2*)(gbias + 64 + 2 * hl);
  float o0 = acc0 * invA + gb0.x;
  float o1 = acc1 * invA + gb0.y;
  float o2 = acc2 * invB + gb1.x;
  float o3 = acc3 * invB + gb1.y;
  // two-moment LN over the 32-lane half (128 channels)
  float s1 = o0 + o1 + o2 + o3;
  float s2 = o0 * o0 + o1 * o1 + o2 * o2 + o3 * o3;
#pragma unroll
  for (int o = 16; o >= 1; o >>= 1) {
    s1 += __shfl_xor(s1, o, 64);
    s2 += __shfl_xor(s2, o, 64);
  }
  float mu = s1 * (1.f / 128.f);
  float var = fmaxf(s2 * (1.f / 128.f) - mu * mu, 0.f);
  float rn = rsqrtf(var + LN_EPS);
  const float2 lg0 = *(const float2*)(lng + 2 * hl);
  const float2 lg1 = *(const float2*)(lng + 64 + 2 * hl);
  const float2 lb0 = *(const float2*)(lnb + 2 * hl);
  const float2 lb1 = *(const float2*)(lnb + 64 + 2 * hl);
  float hn0 = fmaxf((o0 - mu) * rn * lg0.x + lb0.x, 0.f);
  float hn1 = fmaxf((o1 - mu) * rn * lg0.y + lb0.y, 0.f);
  float hn2 = fmaxf((o2 - mu) * rn * lg1.x + lb1.x, 0.f);
  float hn3 = fmaxf((o3 - mu) * rn * lg1.y + lb1.y, 0.f);
  unsigned int* hrow = (unsigned int*)(hb + (size_t)node * HID);
  unsigned int h01 = hrow[hl];        // channels 2hl (low16), 2hl+1 (high16)
  unsigned int h23 = hrow[32 + hl];   // channels 2hl+64, 2hl+65
  float nh0 = bflo(h01) + hn0;
  float nh1 = bfhi(h01) + hn1;
  float nh2 = bflo(h23) + hn2;
  float nh3 = bfhi(h23) + hn3;
  hrow[hl] = bf16pair(nh0, nh1);
  hrow[32 + hl] = bf16pair(nh2, nh3);
}

__device__ __forceinline__ int lower_bound_dev(const int* a, int n, int v) {
  int lo = 0, hi = n;
  while (lo < hi) {
    int mid = (lo + hi) >> 1;
    if (a[mid] < v) lo = mid + 1; else hi = mid;
  }
  return lo;
}

// pooling stage 1: partial sums; grid (B, 4 col-groups, 8 row-chunks)
__global__ __launch_bounds__(256) void pool_part_kernel(const unsigned short* __restrict__ hb,
                                                        const int* __restrict__ batch,
                                                        float* __restrict__ ppart) {
  __shared__ float red[256];
  int b = blockIdx.x, tid = threadIdx.x;
  int start = lower_bound_dev(batch, N_NODES, b);
  int end = lower_bound_dev(batch, N_NODES, b + 1);
  int cl = tid & 31, g = tid >> 5;           // 8 row-groups of 32 lanes
  int c = cl + blockIdx.y * 32;
  int rowoff = blockIdx.z * 8 + g;           // 0..63
  float acc = 0.f;
  for (int n = start + rowoff; n < end; n += 64)
    acc += __uint_as_float((unsigned int)hb[(size_t)n * HID + c] << 16);
  red[tid] = acc;
  __syncthreads();
  if (g == 0) {
    float tot = 0.f;
#pragma unroll
    for (int k = 0; k < 8; ++k) tot += red[cl + 32 * k];
    ppart[((size_t)b * 8 + blockIdx.z) * HID + c] = tot;
  }
}

// pooling stage 2: sum 8 partials, divide by count. grid B, 128 threads.
__global__ __launch_bounds__(128) void pool_reduce_kernel(const float* __restrict__ ppart,
                                                          const int* __restrict__ batch,
                                                          float* __restrict__ pooled) {
  int b = blockIdx.x, c = threadIdx.x;
  int start = lower_bound_dev(batch, N_NODES, b);
  int end = lower_bound_dev(batch, N_NODES, b + 1);
  float tot = 0.f;
#pragma unroll
  for (int z = 0; z < 8; ++z) tot += ppart[((size_t)b * 8 + z) * HID + c];
  float cntf = fmaxf((float)(end - start), 1.f);
  pooled[b * HID + c] = tot / cntf;
}

// One wave per output element (m,c); lane-split K; two independent fused stages.
__global__ __launch_bounds__(256) void gemv2_kernel(
    const float* __restrict__ A1, int lda1, const float* __restrict__ W1,
    const float* __restrict__ b1, float* __restrict__ O1, int ldo1,
    int sh1, int K1, int relu1,
    const float* __restrict__ A2, int lda2, const float* __restrict__ W2,
    const float* __restrict__ b2, float* __restrict__ O2, int ldo2,
    int sh2, int K2, int relu2, int nw1, int nwTot) {
  int gw = (blockIdx.x * 256 + threadIdx.x) >> 6;
  int lane = threadIdx.x & 63;
  if (gw >= nwTot) return;
  const float *A, *W, *b;
  float* O;
  int lda, ldo, K, relu, m, c;
  if (gw < nw1) {
    A = A1; W = W1; b = b1; O = O1; lda = lda1; ldo = ldo1; K = K1; relu = relu1;
    m = gw >> sh1; c = gw & ((1 << sh1) - 1);
  } else {
    int g2 = gw - nw1;
    A = A2; W = W2; b = b2; O = O2; lda = lda2; ldo = ldo2; K = K2; relu = relu2;
    m = g2 >> sh2; c = g2 & ((1 << sh2) - 1);
  }
  const float* a = A + (size_t)m * lda;
  const float* w = W + (size_t)c * K;
  float acc = 0.f;
  for (int k = lane * 2; k < K; k += 128) {
    float2 av = *(const float2*)(a + k);
    float2 wv = *(const float2*)(w + k);
    acc += av.x * wv.x + av.y * wv.y;
  }
  acc = wave_sum64(acc);
  if (lane == 0) {
    acc += b[c];
    if (relu) acc = fmaxf(acc, 0.f);
    O[(size_t)m * ldo + c] = acc;
  }
}

// z1 = relu([att1|att2|seqh|strh] @ p1_W.T + p1_b); wave per (m,c)
__global__ __launch_bounds__(256) void z1_kernel(const float* __restrict__ att1,
                                                 const float* __restrict__ att2,
                                                 const float* __restrict__ seqh,
                                                 const float* __restrict__ strh,
                                                 const float* __restrict__ p1_W,
                                                 const float* __restrict__ p1_b,
                                                 float* __restrict__ z1) {
  int gw = (blockIdx.x * 256 + threadIdx.x) >> 6;
  int lane = threadIdx.x & 63;
  int m = gw >> 8, c = gw & 255;
  const float* segs[4] = {att1 + m * HD, att2 + m * HD, seqh + m * HD, strh + m * HD};
  const float* w = p1_W + (size_t)c * (4 * HD);
  float acc = 0.f;
#pragma unroll
  for (int s = 0; s < 4; ++s) {
    const float* a = segs[s];
#pragma unroll
    for (int k = lane * 2; k < HD; k += 128) {
      float2 av = *(const float2*)(a + k);
      float2 wv = *(const float2*)(w + s * HD + k);
      acc += av.x * wv.x + av.y * wv.y;
    }
  }
  acc = wave_sum64(acc);
  if (lane == 0) z1[m * HD + c] = fmaxf(acc + p1_b[c], 0.f);
}

extern "C" void kernel_launch(void* const* d_in, const int* in_sizes, int n_in,
                              void* d_out, int out_size, void* d_ws, size_t ws_size,
                              hipStream_t stream) {
  const float* seq_emb = (const float*)d_in[0];
  const float* x       = (const float*)d_in[1];
  const int* eidx      = (const int*)d_in[2];
  const int* batch     = (const int*)d_in[3];
  const float* ne_W = (const float*)d_in[4];
  const float* ne_b = (const float*)d_in[5];
  const float* gat_W = (const float*)d_in[6];
  const float* gat_asrc = (const float*)d_in[7];
  const float* gat_adst = (const float*)d_in[8];
  const float* gat_b = (const float*)d_in[9];
  const float* ln_g = (const float*)d_in[10];
  const float* ln_b = (const float*)d_in[11];
  const float* op1_W = (const float*)d_in[12];
  const float* op1_b = (const float*)d_in[13];
  const float* op2_W = (const float*)d_in[14];
  const float* op2_b = (const float*)d_in[15];
  const float* sp_W = (const float*)d_in[16];
  const float* sp_b = (const float*)d_in[17];
  const float* stp_W = (const float*)d_in[18];
  const float* stp_b = (const float*)d_in[19];
  const float* a1_Wi = (const float*)d_in[20];
  const float* a1_bi = (const float*)d_in[21];
  const float* a1_Wo = (const float*)d_in[22];
  const float* a1_bo = (const float*)d_in[23];
  const float* a2_Wi = (const float*)d_in[24];
  const float* a2_bi = (const float*)d_in[25];
  const float* a2_Wo = (const float*)d_in[26];
  const float* a2_bo = (const float*)d_in[27];
  const float* p1_W = (const float*)d_in[28];
  const float* p1_b = (const float*)d_in[29];
  const float* p2_W = (const float*)d_in[30];
  const float* p2_b = (const float*)d_in[31];
  const float* p3_W = (const float*)d_in[32];
  const float* p3_b = (const float*)d_in[33];

  const int E = in_sizes[2] / 2;
  const int* e_src = eidx;
  const int* e_dst = eidx + E;

  char* p = (char*)d_ws;
  auto alloc = [&](size_t bytes) -> void* {
    void* r = p;
    p += (bytes + 255) & ~(size_t)255;
    return r;
  };
  unsigned short* hbuf = (unsigned short*)alloc(sizeof(unsigned short) * (size_t)N_NODES * HID);
  unsigned short* wb   = (unsigned short*)alloc(sizeof(unsigned short) * L_LAYERS * HID * HID);
  unsigned short* was8 = (unsigned short*)alloc(sizeof(unsigned short) * L_LAYERS * 16 * HID);
  unsigned int* xlp = (unsigned int*)alloc(sizeof(unsigned int) * (size_t)N_NODES * 64);
  float* esrc = (float*)alloc(sizeof(float) * (size_t)N_NODES * 4);
  float* edst = (float*)alloc(sizeof(float) * (size_t)N_NODES * 4);
  int* cnt    = (int*)alloc(sizeof(int) * N_NODES);
  int* cur    = (int*)alloc(sizeof(int) * N_NODES);
  int* off    = (int*)alloc(sizeof(int) * (N_NODES + 1));
  int* eadj   = (int*)alloc(sizeof(int) * ((size_t)E + 8));
  int* bsum   = (int*)alloc(sizeof(int) * 128);
  float* ppart = (float*)alloc(sizeof(float) * B_GRAPHS * 8 * HID);
  float* pooled = (float*)alloc(sizeof(float) * B_GRAPHS * HID);
  float* t1B   = (float*)alloc(sizeof(float) * B_GRAPHS * HID);
  float* sembB = (float*)alloc(sizeof(float) * B_GRAPHS * HID);
  float* seqhB = (float*)alloc(sizeof(float) * B_GRAPHS * HD);
  float* strhB = (float*)alloc(sizeof(float) * B_GRAPHS * HD);
  float* v1B   = (float*)alloc(sizeof(float) * B_GRAPHS * HD);
  float* v2B   = (float*)alloc(sizeof(float) * B_GRAPHS * HD);
  float* att1B = (float*)alloc(sizeof(float) * B_GRAPHS * HD);
  float* att2B = (float*)alloc(sizeof(float) * B_GRAPHS * HD);
  float* z1B   = (float*)alloc(sizeof(float) * B_GRAPHS * HD);
  float* z2B   = (float*)alloc(sizeof(float) * B_GRAPHS * (HD / 2));

  hipMemsetAsync(cnt, 0, sizeof(int) * N_NODES, stream);
  hipMemsetAsync(cur, 0, sizeof(int) * N_NODES, stream);
  hipMemsetAsync(eadj + E, 0, sizeof(int) * 8, stream);  // tail-round pad

  const int SCAN_BLKS = (N_NODES + 1023) / 1024;  // 98
  ne_kernel<<<N_NODES * HID / 256, 256, 0, stream>>>(x, ne_W, ne_b, hbuf);
  wcvt_kernel<<<(L_LAYERS * HID * HID + 255) / 256, 256, 0, stream>>>(gat_W, wb);
  wprep_kernel<<<(L_LAYERS * 16 * 128 + 255) / 256, 256, 0, stream>>>(gat_W, gat_asrc, gat_adst, was8);
  hist_kernel<<<(E + 255) / 256, 256, 0, stream>>>(e_dst, cnt, E);
  scan1_kernel<<<SCAN_BLKS, 1024, 0, stream>>>(cnt, off, bsum, N_NODES);
  scan2_kernel<<<1, 64, 0, stream>>>(bsum, SCAN_BLKS);
  scan3_kernel<<<(N_NODES + 256) / 256, 256, 0, stream>>>(bsum, off, N_NODES, E);
  scatter_kernel<<<(E + 255) / 256, 256, 0, stream>>>(e_src, e_dst, off, cur, eadj, E);

  for (int l = 0; l < L_LAYERS; ++l) {
    gat_xl_kernel<<<(N_NODES + 255) / 256, 512, 0, stream>>>(
        hbuf, wb + (size_t)l * HID * HID, was8 + (size_t)l * 16 * HID,
        xlp, esrc, edst);
    gat_agg_kernel<<<N_NODES / 8, 256, 0, stream>>>(
        xlp, esrc, edst, off, eadj, gat_b + l * HID, ln_g + l * HID, ln_b + l * HID,
        hbuf);
  }
  pool_part_kernel<<<dim3(B_GRAPHS, 4, 8), 256, 0, stream>>>(hbuf, batch, ppart);
  pool_reduce_kernel<<<B_GRAPHS, 128, 0, stream>>>(ppart, batch, pooled);

  // ---- head: 8 dependency levels, wave-per-output ----
  const float* a1_Wv = a1_Wi + 2 * HD * HD;
  const float* a1_bv = a1_bi + 2 * HD;
  const float* a2_Wv = a2_Wi + 2 * HD * HD;
  const float* a2_bv = a2_bi + 2 * HD;
  auto nblk = [](int waves) { return (unsigned)((waves + 3) / 4); };

  {
    int nw1 = B_GRAPHS * HD, nwT = nw1 + B_GRAPHS * HID;
    gemv2_kernel<<<nblk(nwT), 256, 0, stream>>>(
        seq_emb, SEQ_LEN, sp_W, sp_b, seqhB, HD, 8, SEQ_LEN, 0,
        pooled, HID, op1_W, op1_b, t1B, HID, 7, HID, 1, nw1, nwT);
  }
  {
    int nw1 = B_GRAPHS * HD, nwT = nw1 + B_GRAPHS * HID;
    gemv2_kernel<<<nblk(nwT), 256, 0, stream>>>(
        seqhB, HD, a2_Wv, a2_bv, v2B, HD, 8, HD, 0,
        t1B, HID, op2_W, op2_b, sembB, HID, 7, HID, 0, nw1, nwT);
  }
  {
    int nw1 = B_GRAPHS * HD, nwT = nw1 + B_GRAPHS * HD;
    gemv2_kernel<<<nblk(nwT), 256, 0, stream>>>(
        v2B, HD, a2_Wo, a2_bo, att2B, HD, 8, HD, 0,
        sembB, HID, stp_W, stp_b, strhB, HD, 8, HID, 0, nw1, nwT);
  }
  {
    int nwT = B_GRAPHS * HD;
    gemv2_kernel<<<nblk(nwT), 256, 0, stream>>>(
        strhB, HD, a1_Wv, a1_bv, v1B, HD, 8, HD, 0,
        nullptr, 0, nullptr, nullptr, nullptr, 0, 0, 0, 0, nwT, nwT);
  }
  {
    int nwT = B_GRAPHS * HD;
    gemv2_kernel<<<nblk(nwT), 256, 0, stream>>>(
        v1B, HD, a1_Wo, a1_bo, att1B, HD, 8, HD, 0,
        nullptr, 0, nullptr, nullptr, nullptr, 0, 0, 0, 0, nwT, nwT);
  }
  z1_kernel<<<nblk(B_GRAPHS * HD), 256, 0, stream>>>(att1B, att2B, seqhB, strhB, p1_W, p1_b, z1B);
  {
    int nwT = B_GRAPHS * (HD / 2);
    gemv2_kernel<<<nblk(nwT), 256, 0, stream>>>(
        z1B, HD, p2_W, p2_b, z2B, HD / 2, 7, HD, 1,
        nullptr, 0, nullptr, nullptr, nullptr, 0, 0, 0, 0, nwT, nwT);
  }
  {
    int nwT = B_GRAPHS;
    gemv2_kernel<<<nblk(nwT), 256, 0, stream>>>(
        z2B, HD / 2, p3_W, p3_b, (float*)d_out, 1, 0, HD / 2, 0,
        nullptr, 0, nullptr, nullptr, nullptr, 0, 0, 0, 0, nwT, nwT);
  }
}